// Round 8
// baseline (194.686 us; speedup 1.0000x reference)
//
#include <hip/hip_runtime.h>

static constexpr int F = 128;   // feature width of x / hidden layers

typedef __attribute__((ext_vector_type(8))) short bf16x8;
typedef __attribute__((ext_vector_type(4))) float f32x4;

__device__ __forceinline__ unsigned short f2b(float f) {   // fp32 -> bf16 RNE
    unsigned int u = __float_as_uint(f);
    u += 0x7fffu + ((u >> 16) & 1u);
    return (unsigned short)(u >> 16);
}
__device__ __forceinline__ float b2f(unsigned int s) {     // low 16 bits -> fp32
    return __uint_as_float(s << 16);
}

// ---------------- prep: cvt x -> bf16, cvt/transpose weights, dst histogram ----------------
// (cnt must be zeroed by the preceding hipMemsetAsync)
__global__ __launch_bounds__(256) void prep_kernel(const float* __restrict__ x,
                                                   unsigned short* __restrict__ xb, int n4,
                                                   const int* __restrict__ dst,
                                                   int* __restrict__ cnt, int nE,
                                                   const float* __restrict__ ws1, const float* __restrict__ wn1,
                                                   const float* __restrict__ ws2, const float* __restrict__ wn2,
                                                   const float* __restrict__ ws3, const float* __restrict__ wn3,
                                                   unsigned short* __restrict__ wt1,
                                                   unsigned short* __restrict__ wt2,
                                                   unsigned short* __restrict__ wt3) {
    const int id = blockIdx.x * 256 + threadIdx.x;
    if (id < n4) {
        const float4 v = reinterpret_cast<const float4*>(x)[id];
        uint2 o;
        o.x = (unsigned)f2b(v.x) | ((unsigned)f2b(v.y) << 16);
        o.y = (unsigned)f2b(v.z) | ((unsigned)f2b(v.w) << 16);
        reinterpret_cast<uint2*>(xb)[id] = o;
    }
    if (id < nE) atomicAdd(&cnt[dst[id]], 1);
    if (id < 128 * 256) {           // wt[col][256] concat(self, neigh), bf16
        const int k = id & 255, c = id >> 8;
        wt1[id] = f2b((k < 128) ? ws1[k * 128 + c] : wn1[(k - 128) * 128 + c]);
        wt2[id] = f2b((k < 128) ? ws2[k * 128 + c] : wn2[(k - 128) * 128 + c]);
    }
    if (id < 64 * 256) {
        const int k = id & 255, c = id >> 8;
        wt3[id] = f2b((k < 128) ? ws3[k * 64 + c] : wn3[(k - 128) * 64 + c]);
    }
}

// ---------------- CSR scan step A: per-block sums (also zeroes fillcnt) ----------------
__global__ __launch_bounds__(256) void scanA_kernel(const int* __restrict__ cnt,
                                                    int* __restrict__ bsums,
                                                    int* __restrict__ fillcnt, int n) {
    __shared__ int s[256];
    const int tid = threadIdx.x;
    const int i = blockIdx.x * 256 + tid;
    if (i < n) fillcnt[i] = 0;
    s[tid] = (i < n) ? cnt[i] : 0;
    __syncthreads();
#pragma unroll
    for (int off = 128; off > 0; off >>= 1) {
        if (tid < off) s[tid] += s[tid + off];
        __syncthreads();
    }
    if (tid == 0) bsums[blockIdx.x] = s[0];
}

// ---------------- CSR scan step B: exclusive scan of block sums (1 block) ----------------
__global__ __launch_bounds__(256) void scanB_kernel(int* __restrict__ bsums, int nb) {
    __shared__ int s[256];
    __shared__ int carry;
    const int tid = threadIdx.x;
    if (tid == 0) carry = 0;
    __syncthreads();
    for (int base = 0; base < nb; base += 256) {
        const int idx = base + tid;
        const int v = (idx < nb) ? bsums[idx] : 0;
        s[tid] = v;
        __syncthreads();
#pragma unroll
        for (int off = 1; off < 256; off <<= 1) {
            int t = (tid >= off) ? s[tid - off] : 0;
            __syncthreads();
            s[tid] += t;
            __syncthreads();
        }
        const int incl = s[tid] + carry;
        if (idx < nb) bsums[idx] = incl - v;   // exclusive
        __syncthreads();
        if (tid == 255) carry = incl;
        __syncthreads();
    }
}

// ---------------- CSR scan step C: per-block scan + offset -> rowptr ----------------
__global__ __launch_bounds__(256) void scanC_kernel(const int* __restrict__ cnt,
                                                    const int* __restrict__ boff,
                                                    int* __restrict__ rowptr, int n) {
    __shared__ int s[256];
    const int tid = threadIdx.x;
    const int i = blockIdx.x * 256 + tid;
    const int v = (i < n) ? cnt[i] : 0;
    s[tid] = v;
    __syncthreads();
#pragma unroll
    for (int off = 1; off < 256; off <<= 1) {
        int t = (tid >= off) ? s[tid - off] : 0;
        __syncthreads();
        s[tid] += t;
        __syncthreads();
    }
    const int incl = s[tid] + boff[blockIdx.x];
    if (i < n) rowptr[i + 1] = incl;
    if (i == 0) rowptr[0] = 0;
}

// ---------------- CSR fill: compact ushort col (1.28 MB -> scatter absorbed by L2) ----------------
__global__ __launch_bounds__(256) void fill_kernel(const int* __restrict__ src,
                                                   const int* __restrict__ dst,
                                                   const int* __restrict__ rowptr,
                                                   int* __restrict__ fillcnt,
                                                   unsigned short* __restrict__ col, int nE) {
    const int e = blockIdx.x * 256 + threadIdx.x;
    if (e < nE) {
        const int d = dst[e];
        const int pos = atomicAdd(&fillcnt[d], 1);
        col[rowptr[d] + pos] = (unsigned short)src[e];
    }
}

// ---------------- gather: nb[v] = mean_{u in N(v)} xb[u]  (bf16 in/out, fp32 accum) ----------------
// 32 lanes per node, 8B per lane. Masked 8-deep loop: ALL edges (incl. tail) processed
// at 8 outstanding loads; clamped index + 0/1 fma weight handles the remainder.
__global__ __launch_bounds__(256) void gather_b_kernel(const unsigned short* __restrict__ xb,
                                                       const int* __restrict__ rowptr,
                                                       const unsigned short* __restrict__ col,
                                                       unsigned short* __restrict__ nb, int nNodes) {
    const int grp  = (blockIdx.x * 256 + threadIdx.x) >> 5;
    const int lane = threadIdx.x & 31;
    if (grp >= nNodes) return;
    const int beg = rowptr[grp];
    const int deg = rowptr[grp + 1] - beg;
    const unsigned short* __restrict__ cp = col + beg;
    const int q = lane << 2;                // ushort index, 4 bf16 per lane

    float s0=0.f,s1=0.f,s2=0.f,s3=0.f;
    float t0=0.f,t1=0.f,t2=0.f,t3=0.f;

    for (int j = 0; j < deg; j += 8) {
        int   idx[8];
        float wg[8];
#pragma unroll
        for (int m = 0; m < 8; ++m) {
            const int jm = j + m;
            idx[m] = cp[jm < deg ? jm : 0];
            wg[m]  = (jm < deg) ? 1.f : 0.f;
        }
        uint2 v[8];
#pragma unroll
        for (int m = 0; m < 8; ++m)
            v[m] = *reinterpret_cast<const uint2*>(xb + (size_t)idx[m] * F + q);
#pragma unroll
        for (int m = 0; m < 8; m += 2) {
            s0 = fmaf(b2f(v[m].x & 0xffffu), wg[m], s0);
            s1 = fmaf(b2f(v[m].x >> 16),     wg[m], s1);
            s2 = fmaf(b2f(v[m].y & 0xffffu), wg[m], s2);
            s3 = fmaf(b2f(v[m].y >> 16),     wg[m], s3);
            t0 = fmaf(b2f(v[m+1].x & 0xffffu), wg[m+1], t0);
            t1 = fmaf(b2f(v[m+1].x >> 16),     wg[m+1], t1);
            t2 = fmaf(b2f(v[m+1].y & 0xffffu), wg[m+1], t2);
            t3 = fmaf(b2f(v[m+1].y >> 16),     wg[m+1], t3);
        }
    }

    const float inv = 1.0f / (float)(deg > 1 ? deg : 1);
    uint2 o;
    o.x = (unsigned)f2b((s0 + t0) * inv) | ((unsigned)f2b((s1 + t1) * inv) << 16);
    o.y = (unsigned)f2b((s2 + t2) * inv) | ((unsigned)f2b((s3 + t3) * inv) << 16);
    *reinterpret_cast<uint2*>(nb + (size_t)grp * F + q) = o;
}

// ---------------- MFMA SAGE layer (col-split waves, B reused across 4 row-tiles) ----------------
// out[r] = act( [xb[r] | nb[r]] @ Wt^T + b ), K=256 concat, bf16 MFMA 16x16x32, fp32 acc.
template<int OUTF, bool RELU, bool OUTB>
__global__ __launch_bounds__(256, 4) void mfma_layer(const unsigned short* __restrict__ xb,
                                                     const unsigned short* __restrict__ nbuf,
                                                     const unsigned short* __restrict__ wt,
                                                     const float* __restrict__ bias,
                                                     void* __restrict__ outp, int nRows)
{
    constexpr int CT = OUTF / 64;          // col-tiles per wave (128->2, 64->1)
    __shared__ unsigned short Acat[64 * 256];   // 32 KB

    const int tid  = threadIdx.x;
    const int row0 = blockIdx.x * 64;

    // ---- stage 64 rows x (128 self + 128 neigh) bf16, 16B chunks, XOR swizzle ----
    for (int i = tid; i < 2048; i += 256) {
        const int r  = i >> 5;             // 0..63
        const int ch = i & 31;             // 0..31 (0-15 self, 16-31 neigh)
        const int g  = row0 + r;
        uint4 v = make_uint4(0u, 0u, 0u, 0u);
        if (g < nRows) {
            const unsigned short* s = (ch < 16) ? xb : nbuf;
            v = *reinterpret_cast<const uint4*>(s + (size_t)g * F + (ch & 15) * 8);
        }
        const int off = (ch * 16) ^ ((r & 7) << 4);
        *reinterpret_cast<uint4*>(reinterpret_cast<char*>(Acat) + r * 512 + off) = v;
    }
    __syncthreads();

    const int lane = tid & 63;
    const int w    = tid >> 6;             // wave 0..3 -> col block w*(OUTF/4)
    const int lm   = lane & 15;
    const int lq   = lane >> 4;            // 0..3
    const int colBase = w * (OUTF / 4);

    f32x4 acc[4][CT];
#pragma unroll
    for (int rt = 0; rt < 4; ++rt)
#pragma unroll
        for (int c = 0; c < CT; ++c) acc[rt][c] = f32x4{0.f, 0.f, 0.f, 0.f};

    const char* abase = reinterpret_cast<const char*>(Acat);

#pragma unroll
    for (int k0 = 0; k0 < 256; k0 += 32) {
        bf16x8 b[CT];
#pragma unroll
        for (int c = 0; c < CT; ++c)
            b[c] = *reinterpret_cast<const bf16x8*>(
                wt + (size_t)(colBase + c * 16 + lm) * 256 + k0 + lq * 8);
#pragma unroll
        for (int rt = 0; rt < 4; ++rt) {
            const int arow = rt * 16 + lm;
            const int aoff = (k0 * 2 + lq * 16) ^ ((arow & 7) << 4);
            const bf16x8 a = *reinterpret_cast<const bf16x8*>(abase + arow * 512 + aoff);
#pragma unroll
            for (int c = 0; c < CT; ++c)
                acc[rt][c] = __builtin_amdgcn_mfma_f32_16x16x32_bf16(a, b[c], acc[rt][c], 0, 0, 0);
        }
    }

    // ---- epilogue: C/D layout col=lane&15, row=(lane>>4)*4+i (m89-verified) ----
#pragma unroll
    for (int rt = 0; rt < 4; ++rt) {
#pragma unroll
        for (int c = 0; c < CT; ++c) {
            const int colIdx = colBase + c * 16 + lm;
            const float bv = bias[colIdx];
#pragma unroll
            for (int i = 0; i < 4; ++i) {
                const int grow = row0 + rt * 16 + lq * 4 + i;
                if (grow >= nRows) continue;
                float v = acc[rt][c][i] + bv;
                if (RELU) v = fmaxf(v, 0.f);
                if (OUTB) ((unsigned short*)outp)[(size_t)grow * F + colIdx] = f2b(v);
                else      ((float*)outp)[(size_t)grow * OUTF + colIdx] = v;
            }
        }
    }
}

extern "C" void kernel_launch(void* const* d_in, const int* in_sizes, int n_in,
                              void* d_out, int out_size, void* d_ws, size_t ws_size,
                              hipStream_t stream) {
    const float* x   = (const float*)d_in[0];
    const int*   src = (const int*)  d_in[1];
    const int*   dst = (const int*)  d_in[2];
    const float* ws1 = (const float*)d_in[3];
    const float* wn1 = (const float*)d_in[4];
    const float* b1  = (const float*)d_in[5];
    const float* ws2 = (const float*)d_in[6];
    const float* wn2 = (const float*)d_in[7];
    const float* b2  = (const float*)d_in[8];
    const float* ws3 = (const float*)d_in[9];
    const float* wn3 = (const float*)d_in[10];
    const float* b3  = (const float*)d_in[11];
    float* out = (float*)d_out;

    const int N = in_sizes[0] / F;   // 50000
    const int E = in_sizes[1];       // 640000

    const int nScanBlocks = (N + 255) / 256;   // 196

    // ---- workspace: cnt | bsums | rowptr | fillcnt | colu(ushort) | xb | nb | h1b | h2b | wt ----
    char* w = (char*)d_ws;
    const size_t cntBytes = ((size_t)N * 4 + 511) & ~(size_t)511;
    const size_t bsBytes  = ((size_t)nScanBlocks * 4 + 511) & ~(size_t)511;
    const size_t rpBytes  = ((size_t)(N + 1) * 4 + 511) & ~(size_t)511;
    const size_t fcBytes  = cntBytes;
    const size_t colBytes = ((size_t)E * 2 + 511) & ~(size_t)511;
    int*            cnt     = (int*)(w);
    int*            bsums   = (int*)(w + cntBytes);
    int*            rowptr  = (int*)(w + cntBytes + bsBytes);
    int*            fillcnt = (int*)(w + cntBytes + bsBytes + rpBytes);
    unsigned short* colu    = (unsigned short*)(w + cntBytes + bsBytes + rpBytes + fcBytes);
    unsigned short* xb      = (unsigned short*)(w + cntBytes + bsBytes + rpBytes + fcBytes + colBytes);
    unsigned short* nb      = xb  + (size_t)N * F;
    unsigned short* h1b     = nb  + (size_t)N * F;
    unsigned short* h2b     = h1b + (size_t)N * F;
    unsigned short* wt1     = h2b + (size_t)N * F;
    unsigned short* wt2     = wt1 + 128 * 256;
    unsigned short* wt3     = wt2 + 128 * 256;

    const dim3 blk(256);
    const int n4         = N * F / 4;
    const int prepGrid   = (n4 + 255) / 256;
    const int edgeGrid   = (E + 255) / 256;
    const int gatherGrid = (int)(((size_t)N * 32 + 255) / 256);
    const int mfmaGrid   = (N + 63) / 64;

    // ---- build compact CSR (hist folded into prep; scatter into 1.28MB L2-resident col) ----
    hipMemsetAsync(cnt, 0, (size_t)N * 4, stream);
    prep_kernel<<<prepGrid, blk, 0, stream>>>(x, xb, n4, dst, cnt, E,
                                              ws1, wn1, ws2, wn2, ws3, wn3, wt1, wt2, wt3);
    scanA_kernel<<<nScanBlocks, blk, 0, stream>>>(cnt, bsums, fillcnt, N);
    scanB_kernel<<<1, blk, 0, stream>>>(bsums, nScanBlocks);
    scanC_kernel<<<nScanBlocks, blk, 0, stream>>>(cnt, bsums, rowptr, N);
    fill_kernel<<<edgeGrid, blk, 0, stream>>>(src, dst, rowptr, fillcnt, colu, E);

    // ---- three layers: gather (bf16) + MFMA GEMM ----
    gather_b_kernel<<<gatherGrid, blk, 0, stream>>>(xb, rowptr, colu, nb, N);
    mfma_layer<128, true,  true ><<<mfmaGrid, blk, 0, stream>>>(xb,  nb, wt1, b1, h1b, N);

    gather_b_kernel<<<gatherGrid, blk, 0, stream>>>(h1b, rowptr, colu, nb, N);
    mfma_layer<128, true,  true ><<<mfmaGrid, blk, 0, stream>>>(h1b, nb, wt2, b2, h2b, N);

    gather_b_kernel<<<gatherGrid, blk, 0, stream>>>(h2b, rowptr, colu, nb, N);
    mfma_layer<64,  false, false><<<mfmaGrid, blk, 0, stream>>>(h2b, nb, wt3, b3, out, N);
}